// Round 15
// baseline (131.205 us; speedup 1.0000x reference)
//
#include <hip/hip_runtime.h>
#include <hip/hip_bf16.h>
#include <stdint.h>

// ---------- types & helpers ----------
typedef __attribute__((ext_vector_type(8))) short bf16x8;
typedef __attribute__((ext_vector_type(4))) short short4v;
typedef __attribute__((ext_vector_type(4))) float f32x4;

#define MFMA16x16x32 __builtin_amdgcn_mfma_f32_16x16x32_bf16
#define CL2F 0.18033688011112042f  // 0.125 * log2(e)

__device__ __forceinline__ short f2b(float f) {
  union { float f; uint32_t u; } x;
  x.f = f;
  uint32_t u = x.u;
  uint32_t r = (u + 0x7FFFu + ((u >> 16) & 1u)) >> 16;  // RNE
  return (short)(uint16_t)r;
}

// HW packed fp32->bf16 (RNE), no builtin on gfx950 (m240) -> inline asm
__device__ __forceinline__ uint32_t cvt_pk_bf16(float lo, float hi) {
  uint32_t r;
  asm volatile("v_cvt_pk_bf16_f32 %0, %1, %2" : "=v"(r) : "v"(lo), "v"(hi));
  return r;
}
// raw v_exp_f32 = 2^x
__device__ __forceinline__ float exp2_fast(float x) {
  float r;
  asm volatile("v_exp_f32 %0, %1" : "=v"(r) : "v"(x));
  return r;
}
__device__ __forceinline__ bf16x8 cvt8(const float4 a, const float4 b) {
  union { uint32_t u[4]; bf16x8 v; } o;
  o.u[0] = cvt_pk_bf16(a.x, a.y);
  o.u[1] = cvt_pk_bf16(a.z, a.w);
  o.u[2] = cvt_pk_bf16(b.x, b.y);
  o.u[3] = cvt_pk_bf16(b.z, b.w);
  return o.v;
}

// async global->LDS, 16B per lane; LDS dest = wave-uniform base + lane*16
__device__ __forceinline__ void async_copy16(const void* g, void* l) {
  __builtin_amdgcn_global_load_lds(
      (const __attribute__((address_space(1))) void*)g,
      (__attribute__((address_space(3))) void*)l, 16, 0, 0);
}

// ---------- prep: weight transpose+convert (z<4) | q/k/v fp32->bf16 (z>=4) ----------
__global__ void prep_kernel(const float* __restrict__ W0,
                            const float* __restrict__ W1,
                            const float* __restrict__ W2,
                            const float* __restrict__ W3,
                            const float* __restrict__ q,
                            const float* __restrict__ k,
                            const float* __restrict__ v,
                            short* __restrict__ Wt,
                            short* __restrict__ xq,
                            short* __restrict__ xk,
                            short* __restrict__ xv) {
  __shared__ short tile[64][72];
  const int z = blockIdx.z;
  const int t = threadIdx.x;
  if (z < 4) {
    const float* W = (z == 0) ? W0 : (z == 1) ? W1 : (z == 2) ? W2 : W3;
    short* Wo = Wt + (size_t)z * 1024 * 1024;
    const int r0 = blockIdx.y * 64;  // src row base (k)
    const int c0 = blockIdx.x * 64;  // src col base (n)
#pragma unroll
    for (int i = 0; i < 4; ++i) {
      const int lin = i * 1024 + t * 4;
      const int r = lin >> 6, c = lin & 63;
      const float4 vv = *(const float4*)&W[(size_t)(r0 + r) * 1024 + c0 + c];
      tile[r][c + 0] = f2b(vv.x);
      tile[r][c + 1] = f2b(vv.y);
      tile[r][c + 2] = f2b(vv.z);
      tile[r][c + 3] = f2b(vv.w);
    }
    __syncthreads();
#pragma unroll
    for (int i = 0; i < 2; ++i) {
      const int lin = i * 2048 + t * 8;
      const int r = lin >> 6, c = lin & 63;  // r = out row (n), c = out col (k)
      bf16x8 ov;
#pragma unroll
      for (int jj = 0; jj < 8; ++jj) ov[jj] = tile[c + jj][r];
      *(bf16x8*)&Wo[(size_t)(c0 + r) * 1024 + r0 + c] = ov;
    }
  } else {
    const float* x = (z == 4) ? q : (z == 5) ? k : v;
    short* yp = (z == 4) ? xq : (z == 5) ? xk : xv;
    const int base = (blockIdx.y * 16 + blockIdx.x) * 256 + t;  // 0..65535
#pragma unroll
    for (int j = 0; j < 8; ++j) {
      const int i = base + j * 65536;  // covers 524288 bf16x8 units
      const float4 a = ((const float4*)x)[2 * i];
      const float4 b = ((const float4*)x)[2 * i + 1];
      ((bf16x8*)yp)[i] = cvt8(a, b);
    }
  }
}

// ---------- QKV projection GEMM + bias (double-buffered, 1 barrier/K-step) ----------
// slice = blockIdx.y + ybase; slice 0 output pre-scaled by CL2F (folded QK scale);
// slice 2 writes Vt transposed. Both operands via global_load_lds into As/Bs
// dbuf (64KB LDS); stage(kt+1) issued POST-barrier -> full MFMA window to land.
__launch_bounds__(256, 2)
__global__ void gemm_qkv_kernel(const short* __restrict__ A0,
                                const short* __restrict__ A1,
                                const short* __restrict__ A2,
                                const short* __restrict__ WtBase,
                                const float* __restrict__ b0,
                                const float* __restrict__ b1,
                                const float* __restrict__ b2,
                                short* __restrict__ C0,
                                short* __restrict__ C1,
                                short* __restrict__ Vt,
                                int ybase) {
  const int K = 1024;
  __shared__ short As[2][128 * 64];
  __shared__ short Bs[2][128 * 64];

  const int y = blockIdx.y + ybase;
  const short* A = (y == 0) ? A0 : (y == 1) ? A1 : A2;
  const short* Wt = WtBase + (size_t)y * 1024 * 1024;
  const float* bias = (y == 0) ? b0 : (y == 1) ? b1 : b2;

  const int tm = blockIdx.x & 31;  // fast index -> same-XCD siblings share tm
  const int tn = blockIdx.x >> 5;
  const int m0 = tm * 128, n0 = tn * 128;

  const int tid = threadIdx.x;
  const int lane = tid & 63;
  const int w = tid >> 6;
  const int wr = w >> 1, wc = w & 1;
  const int hi = lane >> 4, cc = lane & 15;
  const int srow = lane >> 3, schunk = lane & 7;

  f32x4 acc[4][4] = {};

  auto STAGE = [&](int kt, int buf) {
    const int k0 = kt * 64;
#pragma unroll
    for (int i = 0; i < 4; ++i) {
      const int ri = w * 4 + i;
      const int row = ri * 8 + srow;
      const int gch = schunk ^ (row & 7);
      async_copy16(A + (size_t)(m0 + row) * K + (k0 + gch * 8),
                   &As[buf][ri * 512]);
      async_copy16(Wt + (size_t)(n0 + row) * K + (k0 + gch * 8),
                   &Bs[buf][ri * 512]);
    }
  };

  STAGE(0, 0);
  for (int kt = 0; kt < 16; ++kt) {
    const int cur = kt & 1;
    __syncthreads();  // stage(kt) landed; readers of buf[cur^1] (iter kt-1) done
    if (kt < 15) STAGE(kt + 1, cur ^ 1);
#pragma unroll
    for (int kk = 0; kk < 2; ++kk) {
      bf16x8 af[4], bfr[4];
#pragma unroll
      for (int x = 0; x < 4; ++x) {
        const int gch = kk * 4 + hi;
        const int rowA = wr * 64 + x * 16 + cc;
        af[x] = *(const bf16x8*)&As[cur][rowA * 64 + ((gch ^ (rowA & 7)) << 3)];
        const int rowB = wc * 64 + x * 16 + cc;
        bfr[x] = *(const bf16x8*)&Bs[cur][rowB * 64 + ((gch ^ (rowB & 7)) << 3)];
      }
#pragma unroll
      for (int x = 0; x < 4; ++x)
#pragma unroll
        for (int yy = 0; yy < 4; ++yy)
          acc[x][yy] = MFMA16x16x32(af[x], bfr[yy], acc[x][yy], 0, 0, 0);
    }
  }

  short* Cout = (y == 0) ? C0 : C1;
#pragma unroll
  for (int x = 0; x < 4; ++x) {
    const int rbase = m0 + wr * 64 + x * 16 + (hi << 2);
#pragma unroll
    for (int yy = 0; yy < 4; ++yy) {
      const int col = n0 + wc * 64 + yy * 16 + cc;
      const float bv = bias[col];
      if (y == 2) {
        const int b = rbase >> 11, s = rbase & 2047;
        const int hh = col >> 6, d = col & 63;
        short4v pack;
#pragma unroll
        for (int r = 0; r < 4; ++r) pack[r] = f2b(acc[x][yy][r] + bv);
        *(short4v*)&Vt[((size_t)(b * 16 + hh) * 64 + d) * 2048 + s] = pack;
      } else {
#pragma unroll
        for (int r = 0; r < 4; ++r) {
          float val = acc[x][yy][r] + bv;
          if (y == 0) val *= CL2F;  // fold QK softmax scale into qh
          Cout[(size_t)(rbase + r) * 1024 + col] = f2b(val);
        }
      }
    }
  }
}

// ---------- output projection GEMM (dbuf, 1 barrier/K-step; bf16 A, fp32 out) ----------
__launch_bounds__(256, 2)
__global__ void gemm_out_kernel(const short* __restrict__ A,
                                const short* __restrict__ Wt,
                                const float* __restrict__ bias,
                                float* __restrict__ C) {
  const int N = 1024, K = 1024;
  __shared__ short As[2][128 * 64];
  __shared__ short Bs[2][128 * 64];

  const int tm = blockIdx.x & 31;
  const int tn = blockIdx.x >> 5;
  const int m0 = tm * 128, n0 = tn * 128;

  const int tid = threadIdx.x;
  const int lane = tid & 63;
  const int w = tid >> 6;
  const int wr = w >> 1, wc = w & 1;
  const int hi = lane >> 4, cc = lane & 15;
  const int srow = lane >> 3, schunk = lane & 7;

  f32x4 acc[4][4] = {};

  auto STAGE = [&](int kt, int buf) {
    const int k0 = kt * 64;
#pragma unroll
    for (int i = 0; i < 4; ++i) {
      const int ri = w * 4 + i;
      const int row = ri * 8 + srow;
      const int gch = schunk ^ (row & 7);
      async_copy16(A + (size_t)(m0 + row) * K + (k0 + gch * 8),
                   &As[buf][ri * 512]);
      async_copy16(Wt + (size_t)(n0 + row) * K + (k0 + gch * 8),
                   &Bs[buf][ri * 512]);
    }
  };

  STAGE(0, 0);
  for (int kt = 0; kt < 16; ++kt) {
    const int cur = kt & 1;
    __syncthreads();
    if (kt < 15) STAGE(kt + 1, cur ^ 1);
#pragma unroll
    for (int kk = 0; kk < 2; ++kk) {
      bf16x8 af[4], bfr[4];
#pragma unroll
      for (int x = 0; x < 4; ++x) {
        const int gch = kk * 4 + hi;
        const int rowA = wr * 64 + x * 16 + cc;
        af[x] = *(const bf16x8*)&As[cur][rowA * 64 + ((gch ^ (rowA & 7)) << 3)];
        const int rowB = wc * 64 + x * 16 + cc;
        bfr[x] = *(const bf16x8*)&Bs[cur][rowB * 64 + ((gch ^ (rowB & 7)) << 3)];
      }
#pragma unroll
      for (int x = 0; x < 4; ++x)
#pragma unroll
        for (int yy = 0; yy < 4; ++yy)
          acc[x][yy] = MFMA16x16x32(af[x], bfr[yy], acc[x][yy], 0, 0, 0);
    }
  }

#pragma unroll
  for (int x = 0; x < 4; ++x) {
    const int rbase = m0 + wr * 64 + x * 16 + (hi << 2);
#pragma unroll
    for (int yy = 0; yy < 4; ++yy) {
      const int col = n0 + wc * 64 + yy * 16 + cc;
      const float bv = bias[col];
#pragma unroll
      for (int r = 0; r < 4; ++r)
        C[(size_t)(rbase + r) * N + col] = acc[x][yy][r] + bv;
    }
  }
}

// ---------- flash attention (T12: P in registers; qh pre-scaled by CL2) ----------
// grid (16, 16, 2) = 512 blocks; 4 waves x 32 q-rows; KVBLK=64, K/V dbuf.
// QK A-rows from sigma-permuted K rows: sigma(n,m)=(n>>1)*32+(m>>2)*8+(n&1)*4+(m&3)
// -> lane (hi,cc) holds scores for kv={kk*32+hi*8+0..7} of q-row cc = PV's
// B-fragment. P never touches LDS. qh carries the 0.125*log2e scale, so
// softmax is exp2(sacc) directly. PV lags one tile (pu/vf in regs).
__launch_bounds__(256, 2)
__global__ void attn_kernel(const short* __restrict__ qh,
                            const short* __restrict__ kh,
                            const short* __restrict__ Vt,
                            short* __restrict__ concat) {
  __shared__ short Ks[2][64 * 64];
  __shared__ short Vs[2][64 * 64];

  const int qb = blockIdx.x;
  const int h = blockIdx.y;
  const int b = blockIdx.z;
  const int tid = threadIdx.x, lane = tid & 63, w = tid >> 6;
  const int hi = lane >> 4, cc = lane & 15;

  const size_t rowbase = (size_t)b * 2048;
  const int q0 = qb * 128 + w * 32;

  // Q fragments, B-operand: col = q, k = hi*8+i (+32 per kk); 2 q-frags
  bf16x8 qf[2][2];
#pragma unroll
  for (int aq = 0; aq < 2; ++aq)
#pragma unroll
    for (int kk = 0; kk < 2; ++kk) {
      const int col = h * 64 + kk * 32 + hi * 8;
      qf[aq][kk] =
          *(const bf16x8*)&qh[(rowbase + q0 + aq * 16 + cc) * 1024 + col];
    }

  f32x4 oacc[2][4] = {};
  float l[2] = {0.f, 0.f};
  bf16x8 vf[2][4];        // lagged V fragments (tile t-1)
  uint32_t pu[2][4][2];   // lagged P: [aq][n][pair], bf16 pairs (kv 4n..4n+3)

  const short* Vth = Vt + (size_t)(b * 16 + h) * 64 * 2048;
  const int srow = lane >> 3, schunk = lane & 7;
  const int fKr = (((cc >> 2) & 1) << 2) | (cc & 3);  // fK(sigma(n,cc)), n-indep

  auto STAGE = [&](int tile, int buf) {
#pragma unroll
    for (int i = 0; i < 2; ++i) {
      const int ri = w * 2 + i;
      const int row = ri * 8 + srow;
      const int gchK = schunk ^ ((((ri) & 1) << 2) | (srow & 3));  // fK(row)
      const int gchV = schunk ^ (row & 7);
      async_copy16(&kh[(rowbase + tile * 64 + row) * 1024 + h * 64 + gchK * 8],
                   &Ks[buf][ri * 512]);
      async_copy16(&Vth[(size_t)row * 2048 + tile * 64 + gchV * 8],
                   &Vs[buf][ri * 512]);
    }
  };
  auto QK = [&](int buf, f32x4 (&sacc)[2][4]) {
#pragma unroll
    for (int kk = 0; kk < 2; ++kk) {
      bf16x8 kf[4];
#pragma unroll
      for (int n = 0; n < 4; ++n) {
        const int row = ((n >> 1) << 5) + (((cc >> 2)) << 3) + ((n & 1) << 2) +
                        (cc & 3);  // sigma(n, cc)
        const int ch = (kk * 4 + hi) ^ fKr;
        kf[n] = *(const bf16x8*)&Ks[buf][row * 64 + (ch << 3)];
      }
#pragma unroll
      for (int aq = 0; aq < 2; ++aq)
#pragma unroll
        for (int n = 0; n < 4; ++n)
          sacc[aq][n] = MFMA16x16x32(kf[n], qf[aq][kk], sacc[aq][n], 0, 0, 0);
    }
  };
  auto LOADV = [&](int buf) {
#pragma unroll
    for (int kvh = 0; kvh < 2; ++kvh) {
      const int ch = (kvh * 4 + hi) ^ (cc & 7);
#pragma unroll
      for (int n = 0; n < 4; ++n)
        vf[kvh][n] =
            *(const bf16x8*)&Vs[buf][(n * 16 + cc) * 64 + (ch << 3)];
    }
  };
  auto SOFTMAX = [&](f32x4 (&sacc)[2][4]) {
#pragma unroll
    for (int aq = 0; aq < 2; ++aq)
#pragma unroll
      for (int n = 0; n < 4; ++n) {
        const float p0 = exp2_fast(sacc[aq][n][0]);  // scale folded into qh
        const float p1 = exp2_fast(sacc[aq][n][1]);
        const float p2 = exp2_fast(sacc[aq][n][2]);
        const float p3 = exp2_fast(sacc[aq][n][3]);
        l[aq] += (p0 + p1) + (p2 + p3);
        pu[aq][n][0] = cvt_pk_bf16(p0, p1);
        pu[aq][n][1] = cvt_pk_bf16(p2, p3);
      }
  };
  auto PV = [&]() {
#pragma unroll
    for (int kvh = 0; kvh < 2; ++kvh)
#pragma unroll
      for (int aq = 0; aq < 2; ++aq) {
        union { uint32_t u[4]; bf16x8 v; } pf;
        pf.u[0] = pu[aq][2 * kvh][0];
        pf.u[1] = pu[aq][2 * kvh][1];
        pf.u[2] = pu[aq][2 * kvh + 1][0];
        pf.u[3] = pu[aq][2 * kvh + 1][1];
#pragma unroll
        for (int n = 0; n < 4; ++n)
          oacc[aq][n] = MFMA16x16x32(vf[kvh][n], pf.v, oacc[aq][n], 0, 0, 0);
      }
  };

  // prologue: stage tile 0, then peeled iteration 0 (no PV yet)
  STAGE(0, 0);
  __syncthreads();
  {
    STAGE(1, 1);
    f32x4 sacc[2][4] = {};
    QK(0, sacc);
    LOADV(0);
    SOFTMAX(sacc);
    __syncthreads();  // stage(1) drained
  }

  for (int t = 1; t < 32; ++t) {
    const int cur = t & 1;
    if (t + 1 < 32) STAGE(t + 1, cur ^ 1);
    f32x4 sacc[2][4] = {};
    QK(cur, sacc);   // MFMA tile t
    PV();            // MFMA tile t-1 (regs) — independent, fills matrix pipe
    LOADV(cur);      // V(t) -> vf (after PV consumed V(t-1))
    SOFTMAX(sacc);   // VALU; overwrites pu with P(t)
    __syncthreads();
  }
  PV();  // lagged PV for tile 31

  // epilogue: finish row-sums across the 4 lanes sharing q, normalize, store
#pragma unroll
  for (int aq = 0; aq < 2; ++aq) {
    float lv = l[aq];
    lv += __shfl_xor(lv, 16);
    lv += __shfl_xor(lv, 32);
    const float inv = 1.0f / lv;
    const size_t grow = rowbase + q0 + aq * 16 + cc;
#pragma unroll
    for (int n = 0; n < 4; ++n)
#pragma unroll
      for (int r = 0; r < 4; ++r) {
        const int d = n * 16 + hi * 4 + r;
        concat[grow * 1024 + h * 64 + d] = f2b(oacc[aq][n][r] * inv);
      }
  }
}

// ---------- launch ----------
extern "C" void kernel_launch(void* const* d_in, const int* in_sizes, int n_in,
                              void* d_out, int out_size, void* d_ws, size_t ws_size,
                              hipStream_t stream) {
  const float* q = (const float*)d_in[0];
  const float* k = (const float*)d_in[1];
  const float* v = (const float*)d_in[2];
  const float* WQ = (const float*)d_in[3];
  const float* bQ = (const float*)d_in[4];
  const float* WK = (const float*)d_in[5];
  const float* bK = (const float*)d_in[6];
  const float* WV = (const float*)d_in[7];
  const float* bV = (const float*)d_in[8];
  const float* WO = (const float*)d_in[9];
  const float* bO = (const float*)d_in[10];

  char* ws = (char*)d_ws;
  const size_t MB = 1024 * 1024;
  short* Wt = (short*)ws;              // 0..8   MB: weights bf16, transposed
  short* xq = (short*)(ws + 8 * MB);   // 8..16  MB: bf16(q)
  short* xk = (short*)(ws + 16 * MB);  // 16..24 MB: bf16(k); later concat
  short* xv = (short*)(ws + 24 * MB);  // 24..32 MB: bf16(v)
  short* qh = (short*)(ws + 32 * MB);  // 32..40 MB
  short* kh = (short*)(ws + 40 * MB);  // 40..48 MB
  short* concat = xk;                  // xk dead after projections

  // 1) prep: weight transpose+convert (z<4) and q/k/v cvt (z>=4)
  prep_kernel<<<dim3(16, 16, 7), 256, 0, stream>>>(WQ, WK, WV, WO, q, k, v,
                                                   Wt, xq, xk, xv);

  // 2) QKV projections
  if (ws_size >= 56 * MB) {
    // single dispatch, 768 blocks; Vt gets its own slot
    short* Vt = (short*)(ws + 48 * MB);  // 48..56 MB
    gemm_qkv_kernel<<<dim3(256, 3), 256, 0, stream>>>(
        xq, xk, xv, Wt, bQ, bK, bV, qh, kh, Vt, 0);
    attn_kernel<<<dim3(16, 16, 2), 256, 0, stream>>>(qh, kh, Vt, concat);
  } else {
    // proven 48 MB path: two dispatches, Vt aliases xq (dead after 2a)
    short* Vt = xq;
    gemm_qkv_kernel<<<dim3(256, 2), 256, 0, stream>>>(
        xq, xk, xv, Wt, bQ, bK, bV, qh, kh, Vt, 0);
    gemm_qkv_kernel<<<dim3(256, 1), 256, 0, stream>>>(
        xq, xk, xv, Wt, bQ, bK, bV, qh, kh, Vt, 2);
    attn_kernel<<<dim3(16, 16, 2), 256, 0, stream>>>(qh, kh, Vt, concat);
  }

  // 3) output projection -> d_out (fp32)
  gemm_out_kernel<<<256, 256, 0, stream>>>(concat, Wt + 3 * MB, bO,
                                           (float*)d_out);
}

// Round 16
// 113.718 us; speedup vs baseline: 1.1538x; 1.1538x over previous
//
#include <hip/hip_runtime.h>
#include <hip/hip_bf16.h>
#include <stdint.h>

// ---------- types & helpers ----------
typedef __attribute__((ext_vector_type(8))) short bf16x8;
typedef __attribute__((ext_vector_type(4))) short short4v;
typedef __attribute__((ext_vector_type(4))) float f32x4;

#define MFMA16x16x32 __builtin_amdgcn_mfma_f32_16x16x32_bf16
#define CL2F 0.18033688011112042f  // 0.125 * log2(e)

__device__ __forceinline__ short f2b(float f) {
  union { float f; uint32_t u; } x;
  x.f = f;
  uint32_t u = x.u;
  uint32_t r = (u + 0x7FFFu + ((u >> 16) & 1u)) >> 16;  // RNE
  return (short)(uint16_t)r;
}

// HW packed fp32->bf16 (RNE), no builtin on gfx950 (m240) -> inline asm
__device__ __forceinline__ uint32_t cvt_pk_bf16(float lo, float hi) {
  uint32_t r;
  asm volatile("v_cvt_pk_bf16_f32 %0, %1, %2" : "=v"(r) : "v"(lo), "v"(hi));
  return r;
}
// raw v_exp_f32 = 2^x
__device__ __forceinline__ float exp2_fast(float x) {
  float r;
  asm volatile("v_exp_f32 %0, %1" : "=v"(r) : "v"(x));
  return r;
}
__device__ __forceinline__ bf16x8 cvt8(const float4 a, const float4 b) {
  union { uint32_t u[4]; bf16x8 v; } o;
  o.u[0] = cvt_pk_bf16(a.x, a.y);
  o.u[1] = cvt_pk_bf16(a.z, a.w);
  o.u[2] = cvt_pk_bf16(b.x, b.y);
  o.u[3] = cvt_pk_bf16(b.z, b.w);
  return o.v;
}

// async global->LDS, 16B per lane; LDS dest = wave-uniform base + lane*16
__device__ __forceinline__ void async_copy16(const void* g, void* l) {
  __builtin_amdgcn_global_load_lds(
      (const __attribute__((address_space(1))) void*)g,
      (__attribute__((address_space(3))) void*)l, 16, 0, 0);
}

// ---------- prep: weight transpose+convert (z<4) | q/k/v fp32->bf16 (z>=4) ----------
__global__ void prep_kernel(const float* __restrict__ W0,
                            const float* __restrict__ W1,
                            const float* __restrict__ W2,
                            const float* __restrict__ W3,
                            const float* __restrict__ q,
                            const float* __restrict__ k,
                            const float* __restrict__ v,
                            short* __restrict__ Wt,
                            short* __restrict__ xq,
                            short* __restrict__ xk,
                            short* __restrict__ xv) {
  __shared__ short tile[64][72];
  const int z = blockIdx.z;
  const int t = threadIdx.x;
  if (z < 4) {
    const float* W = (z == 0) ? W0 : (z == 1) ? W1 : (z == 2) ? W2 : W3;
    short* Wo = Wt + (size_t)z * 1024 * 1024;
    const int r0 = blockIdx.y * 64;  // src row base (k)
    const int c0 = blockIdx.x * 64;  // src col base (n)
#pragma unroll
    for (int i = 0; i < 4; ++i) {
      const int lin = i * 1024 + t * 4;
      const int r = lin >> 6, c = lin & 63;
      const float4 vv = *(const float4*)&W[(size_t)(r0 + r) * 1024 + c0 + c];
      tile[r][c + 0] = f2b(vv.x);
      tile[r][c + 1] = f2b(vv.y);
      tile[r][c + 2] = f2b(vv.z);
      tile[r][c + 3] = f2b(vv.w);
    }
    __syncthreads();
#pragma unroll
    for (int i = 0; i < 2; ++i) {
      const int lin = i * 2048 + t * 8;
      const int r = lin >> 6, c = lin & 63;  // r = out row (n), c = out col (k)
      bf16x8 ov;
#pragma unroll
      for (int jj = 0; jj < 8; ++jj) ov[jj] = tile[c + jj][r];
      *(bf16x8*)&Wo[(size_t)(c0 + r) * 1024 + r0 + c] = ov;
    }
  } else {
    const float* x = (z == 4) ? q : (z == 5) ? k : v;
    short* yp = (z == 4) ? xq : (z == 5) ? xk : xv;
    const int base = (blockIdx.y * 16 + blockIdx.x) * 256 + t;  // 0..65535
#pragma unroll
    for (int j = 0; j < 8; ++j) {
      const int i = base + j * 65536;  // covers 524288 bf16x8 units
      const float4 a = ((const float4*)x)[2 * i];
      const float4 b = ((const float4*)x)[2 * i + 1];
      ((bf16x8*)yp)[i] = cvt8(a, b);
    }
  }
}

// ---------- QKV projection GEMM + bias (single-buffer, proven structure) ----------
// slice = blockIdx.y + ybase; slice 0 output pre-scaled by CL2F (folded QK
// scale); slice 2 writes Vt transposed. 32KB LDS -> 3 blocks/CU resident on
// the 768-block grid; cross-block overlap hides stage latency (m114).
__launch_bounds__(256, 2)
__global__ void gemm_qkv_kernel(const short* __restrict__ A0,
                                const short* __restrict__ A1,
                                const short* __restrict__ A2,
                                const short* __restrict__ WtBase,
                                const float* __restrict__ b0,
                                const float* __restrict__ b1,
                                const float* __restrict__ b2,
                                short* __restrict__ C0,
                                short* __restrict__ C1,
                                short* __restrict__ Vt,
                                int ybase) {
  const int K = 1024;
  __shared__ short As[128 * 64];
  __shared__ short Bs[128 * 64];

  const int y = blockIdx.y + ybase;
  const short* A = (y == 0) ? A0 : (y == 1) ? A1 : A2;
  const short* Wt = WtBase + (size_t)y * 1024 * 1024;
  const float* bias = (y == 0) ? b0 : (y == 1) ? b1 : b2;

  const int tm = blockIdx.x & 31;  // fast index -> same-XCD siblings share tm
  const int tn = blockIdx.x >> 5;
  const int m0 = tm * 128, n0 = tn * 128;

  const int tid = threadIdx.x;
  const int lane = tid & 63;
  const int w = tid >> 6;
  const int wr = w >> 1, wc = w & 1;
  const int hi = lane >> 4, cc = lane & 15;
  const int srow = lane >> 3, schunk = lane & 7;

  f32x4 acc[4][4] = {};

  for (int kt = 0; kt < 16; ++kt) {
    const int k0 = kt * 64;
#pragma unroll
    for (int i = 0; i < 4; ++i) {
      const int ri = w * 4 + i;
      const int row = ri * 8 + srow;
      const int gch = schunk ^ (row & 7);
      async_copy16(A + (size_t)(m0 + row) * K + (k0 + gch * 8), &As[ri * 512]);
      async_copy16(Wt + (size_t)(n0 + row) * K + (k0 + gch * 8), &Bs[ri * 512]);
    }
    __syncthreads();
#pragma unroll
    for (int kk = 0; kk < 2; ++kk) {
      bf16x8 af[4], bfr[4];
#pragma unroll
      for (int x = 0; x < 4; ++x) {
        const int gch = kk * 4 + hi;
        const int rowA = wr * 64 + x * 16 + cc;
        af[x] = *(const bf16x8*)&As[rowA * 64 + ((gch ^ (rowA & 7)) << 3)];
        const int rowB = wc * 64 + x * 16 + cc;
        bfr[x] = *(const bf16x8*)&Bs[rowB * 64 + ((gch ^ (rowB & 7)) << 3)];
      }
#pragma unroll
      for (int x = 0; x < 4; ++x)
#pragma unroll
        for (int yy = 0; yy < 4; ++yy)
          acc[x][yy] = MFMA16x16x32(af[x], bfr[yy], acc[x][yy], 0, 0, 0);
    }
    __syncthreads();
  }

  short* Cout = (y == 0) ? C0 : C1;
#pragma unroll
  for (int x = 0; x < 4; ++x) {
    const int rbase = m0 + wr * 64 + x * 16 + (hi << 2);
#pragma unroll
    for (int yy = 0; yy < 4; ++yy) {
      const int col = n0 + wc * 64 + yy * 16 + cc;
      const float bv = bias[col];
      if (y == 2) {
        const int b = rbase >> 11, s = rbase & 2047;
        const int hh = col >> 6, d = col & 63;
        short4v pack;
#pragma unroll
        for (int r = 0; r < 4; ++r) pack[r] = f2b(acc[x][yy][r] + bv);
        *(short4v*)&Vt[((size_t)(b * 16 + hh) * 64 + d) * 2048 + s] = pack;
      } else {
#pragma unroll
        for (int r = 0; r < 4; ++r) {
          float val = acc[x][yy][r] + bv;
          if (y == 0) val *= CL2F;  // fold QK softmax scale into qh
          Cout[(size_t)(rbase + r) * 1024 + col] = f2b(val);
        }
      }
    }
  }
}

// ---------- output projection GEMM (single-buffer; bf16 A, fp32 out) ----------
__launch_bounds__(256, 2)
__global__ void gemm_out_kernel(const short* __restrict__ A,
                                const short* __restrict__ Wt,
                                const float* __restrict__ bias,
                                float* __restrict__ C) {
  const int N = 1024, K = 1024;
  __shared__ short As[128 * 64];
  __shared__ short Bs[128 * 64];

  const int tm = blockIdx.x & 31;
  const int tn = blockIdx.x >> 5;
  const int m0 = tm * 128, n0 = tn * 128;

  const int tid = threadIdx.x;
  const int lane = tid & 63;
  const int w = tid >> 6;
  const int wr = w >> 1, wc = w & 1;
  const int hi = lane >> 4, cc = lane & 15;
  const int srow = lane >> 3, schunk = lane & 7;

  f32x4 acc[4][4] = {};

  for (int kt = 0; kt < 16; ++kt) {
    const int k0 = kt * 64;
#pragma unroll
    for (int i = 0; i < 4; ++i) {
      const int ri = w * 4 + i;
      const int row = ri * 8 + srow;
      const int gch = schunk ^ (row & 7);
      async_copy16(A + (size_t)(m0 + row) * K + (k0 + gch * 8), &As[ri * 512]);
      async_copy16(Wt + (size_t)(n0 + row) * K + (k0 + gch * 8), &Bs[ri * 512]);
    }
    __syncthreads();
#pragma unroll
    for (int kk = 0; kk < 2; ++kk) {
      bf16x8 af[4], bfr[4];
#pragma unroll
      for (int x = 0; x < 4; ++x) {
        const int gch = kk * 4 + hi;
        const int rowA = wr * 64 + x * 16 + cc;
        af[x] = *(const bf16x8*)&As[rowA * 64 + ((gch ^ (rowA & 7)) << 3)];
        const int rowB = wc * 64 + x * 16 + cc;
        bfr[x] = *(const bf16x8*)&Bs[rowB * 64 + ((gch ^ (rowB & 7)) << 3)];
      }
#pragma unroll
      for (int x = 0; x < 4; ++x)
#pragma unroll
        for (int yy = 0; yy < 4; ++yy)
          acc[x][yy] = MFMA16x16x32(af[x], bfr[yy], acc[x][yy], 0, 0, 0);
    }
    __syncthreads();
  }

#pragma unroll
  for (int x = 0; x < 4; ++x) {
    const int rbase = m0 + wr * 64 + x * 16 + (hi << 2);
#pragma unroll
    for (int yy = 0; yy < 4; ++yy) {
      const int col = n0 + wc * 64 + yy * 16 + cc;
      const float bv = bias[col];
#pragma unroll
      for (int r = 0; r < 4; ++r)
        C[(size_t)(rbase + r) * N + col] = acc[x][yy][r] + bv;
    }
  }
}

// ---------- flash attention (T12: P in registers; qh pre-scaled by CL2) ----------
// grid (16, 16, 2) = 512 blocks; 4 waves x 32 q-rows; KVBLK=64, K/V dbuf.
// QK A-rows from sigma-permuted K rows: sigma(n,m)=(n>>1)*32+(m>>2)*8+(n&1)*4+(m&3)
// -> lane (hi,cc) holds scores for kv={kk*32+hi*8+0..7} of q-row cc = PV's
// B-fragment. P never touches LDS. qh carries the 0.125*log2e scale, so
// softmax is exp2(sacc) directly. PV lags one tile (pu/vf in regs).
__launch_bounds__(256, 2)
__global__ void attn_kernel(const short* __restrict__ qh,
                            const short* __restrict__ kh,
                            const short* __restrict__ Vt,
                            short* __restrict__ concat) {
  __shared__ short Ks[2][64 * 64];
  __shared__ short Vs[2][64 * 64];

  const int qb = blockIdx.x;
  const int h = blockIdx.y;
  const int b = blockIdx.z;
  const int tid = threadIdx.x, lane = tid & 63, w = tid >> 6;
  const int hi = lane >> 4, cc = lane & 15;

  const size_t rowbase = (size_t)b * 2048;
  const int q0 = qb * 128 + w * 32;

  // Q fragments, B-operand: col = q, k = hi*8+i (+32 per kk); 2 q-frags
  bf16x8 qf[2][2];
#pragma unroll
  for (int aq = 0; aq < 2; ++aq)
#pragma unroll
    for (int kk = 0; kk < 2; ++kk) {
      const int col = h * 64 + kk * 32 + hi * 8;
      qf[aq][kk] =
          *(const bf16x8*)&qh[(rowbase + q0 + aq * 16 + cc) * 1024 + col];
    }

  f32x4 oacc[2][4] = {};
  float l[2] = {0.f, 0.f};
  bf16x8 vf[2][4];        // lagged V fragments (tile t-1)
  uint32_t pu[2][4][2];   // lagged P: [aq][n][pair], bf16 pairs (kv 4n..4n+3)

  const short* Vth = Vt + (size_t)(b * 16 + h) * 64 * 2048;
  const int srow = lane >> 3, schunk = lane & 7;
  const int fKr = (((cc >> 2) & 1) << 2) | (cc & 3);  // fK(sigma(n,cc)), n-indep

  auto STAGE = [&](int tile, int buf) {
#pragma unroll
    for (int i = 0; i < 2; ++i) {
      const int ri = w * 2 + i;
      const int row = ri * 8 + srow;
      const int gchK = schunk ^ ((((ri) & 1) << 2) | (srow & 3));  // fK(row)
      const int gchV = schunk ^ (row & 7);
      async_copy16(&kh[(rowbase + tile * 64 + row) * 1024 + h * 64 + gchK * 8],
                   &Ks[buf][ri * 512]);
      async_copy16(&Vth[(size_t)row * 2048 + tile * 64 + gchV * 8],
                   &Vs[buf][ri * 512]);
    }
  };
  auto QK = [&](int buf, f32x4 (&sacc)[2][4]) {
#pragma unroll
    for (int kk = 0; kk < 2; ++kk) {
      bf16x8 kf[4];
#pragma unroll
      for (int n = 0; n < 4; ++n) {
        const int row = ((n >> 1) << 5) + (((cc >> 2)) << 3) + ((n & 1) << 2) +
                        (cc & 3);  // sigma(n, cc)
        const int ch = (kk * 4 + hi) ^ fKr;
        kf[n] = *(const bf16x8*)&Ks[buf][row * 64 + (ch << 3)];
      }
#pragma unroll
      for (int aq = 0; aq < 2; ++aq)
#pragma unroll
        for (int n = 0; n < 4; ++n)
          sacc[aq][n] = MFMA16x16x32(kf[n], qf[aq][kk], sacc[aq][n], 0, 0, 0);
    }
  };
  auto LOADV = [&](int buf) {
#pragma unroll
    for (int kvh = 0; kvh < 2; ++kvh) {
      const int ch = (kvh * 4 + hi) ^ (cc & 7);
#pragma unroll
      for (int n = 0; n < 4; ++n)
        vf[kvh][n] =
            *(const bf16x8*)&Vs[buf][(n * 16 + cc) * 64 + (ch << 3)];
    }
  };
  auto SOFTMAX = [&](f32x4 (&sacc)[2][4]) {
#pragma unroll
    for (int aq = 0; aq < 2; ++aq)
#pragma unroll
      for (int n = 0; n < 4; ++n) {
        const float p0 = exp2_fast(sacc[aq][n][0]);  // scale folded into qh
        const float p1 = exp2_fast(sacc[aq][n][1]);
        const float p2 = exp2_fast(sacc[aq][n][2]);
        const float p3 = exp2_fast(sacc[aq][n][3]);
        l[aq] += (p0 + p1) + (p2 + p3);
        pu[aq][n][0] = cvt_pk_bf16(p0, p1);
        pu[aq][n][1] = cvt_pk_bf16(p2, p3);
      }
  };
  auto PV = [&]() {
#pragma unroll
    for (int kvh = 0; kvh < 2; ++kvh)
#pragma unroll
      for (int aq = 0; aq < 2; ++aq) {
        union { uint32_t u[4]; bf16x8 v; } pf;
        pf.u[0] = pu[aq][2 * kvh][0];
        pf.u[1] = pu[aq][2 * kvh][1];
        pf.u[2] = pu[aq][2 * kvh + 1][0];
        pf.u[3] = pu[aq][2 * kvh + 1][1];
#pragma unroll
        for (int n = 0; n < 4; ++n)
          oacc[aq][n] = MFMA16x16x32(vf[kvh][n], pf.v, oacc[aq][n], 0, 0, 0);
      }
  };

  // prologue: stage tile 0, then peeled iteration 0 (no PV yet)
  STAGE(0, 0);
  __syncthreads();
  {
    STAGE(1, 1);
    f32x4 sacc[2][4] = {};
    QK(0, sacc);
    LOADV(0);
    SOFTMAX(sacc);
    __syncthreads();  // stage(1) drained
  }

  for (int t = 1; t < 32; ++t) {
    const int cur = t & 1;
    if (t + 1 < 32) STAGE(t + 1, cur ^ 1);
    f32x4 sacc[2][4] = {};
    QK(cur, sacc);   // MFMA tile t
    PV();            // MFMA tile t-1 (regs) — independent, fills matrix pipe
    LOADV(cur);      // V(t) -> vf (after PV consumed V(t-1))
    SOFTMAX(sacc);   // VALU; overwrites pu with P(t)
    __syncthreads();
  }
  PV();  // lagged PV for tile 31

  // epilogue: finish row-sums across the 4 lanes sharing q, normalize, store
#pragma unroll
  for (int aq = 0; aq < 2; ++aq) {
    float lv = l[aq];
    lv += __shfl_xor(lv, 16);
    lv += __shfl_xor(lv, 32);
    const float inv = 1.0f / lv;
    const size_t grow = rowbase + q0 + aq * 16 + cc;
#pragma unroll
    for (int n = 0; n < 4; ++n)
#pragma unroll
      for (int r = 0; r < 4; ++r) {
        const int d = n * 16 + hi * 4 + r;
        concat[grow * 1024 + h * 64 + d] = f2b(oacc[aq][n][r] * inv);
      }
  }
}

// ---------- launch ----------
extern "C" void kernel_launch(void* const* d_in, const int* in_sizes, int n_in,
                              void* d_out, int out_size, void* d_ws, size_t ws_size,
                              hipStream_t stream) {
  const float* q = (const float*)d_in[0];
  const float* k = (const float*)d_in[1];
  const float* v = (const float*)d_in[2];
  const float* WQ = (const float*)d_in[3];
  const float* bQ = (const float*)d_in[4];
  const float* WK = (const float*)d_in[5];
  const float* bK = (const float*)d_in[6];
  const float* WV = (const float*)d_in[7];
  const float* bV = (const float*)d_in[8];
  const float* WO = (const float*)d_in[9];
  const float* bO = (const float*)d_in[10];

  char* ws = (char*)d_ws;
  const size_t MB = 1024 * 1024;
  short* Wt = (short*)ws;              // 0..8   MB: weights bf16, transposed
  short* xq = (short*)(ws + 8 * MB);   // 8..16  MB: bf16(q)
  short* xk = (short*)(ws + 16 * MB);  // 16..24 MB: bf16(k); later concat
  short* xv = (short*)(ws + 24 * MB);  // 24..32 MB: bf16(v)
  short* qh = (short*)(ws + 32 * MB);  // 32..40 MB
  short* kh = (short*)(ws + 40 * MB);  // 40..48 MB
  short* concat = xk;                  // xk dead after projections

  // 1) prep: weight transpose+convert (z<4) and q/k/v cvt (z>=4)
  prep_kernel<<<dim3(16, 16, 7), 256, 0, stream>>>(WQ, WK, WV, WO, q, k, v,
                                                   Wt, xq, xk, xv);

  // 2) QKV projections
  if (ws_size >= 56 * MB) {
    // single dispatch, 768 blocks = 3 blocks/CU; Vt gets its own slot
    short* Vt = (short*)(ws + 48 * MB);  // 48..56 MB
    gemm_qkv_kernel<<<dim3(256, 3), 256, 0, stream>>>(
        xq, xk, xv, Wt, bQ, bK, bV, qh, kh, Vt, 0);
    attn_kernel<<<dim3(16, 16, 2), 256, 0, stream>>>(qh, kh, Vt, concat);
  } else {
    // proven 48 MB path: two dispatches, Vt aliases xq (dead after 2a)
    short* Vt = xq;
    gemm_qkv_kernel<<<dim3(256, 2), 256, 0, stream>>>(
        xq, xk, xv, Wt, bQ, bK, bV, qh, kh, Vt, 0);
    gemm_qkv_kernel<<<dim3(256, 1), 256, 0, stream>>>(
        xq, xk, xv, Wt, bQ, bK, bV, qh, kh, Vt, 2);
    attn_kernel<<<dim3(16, 16, 2), 256, 0, stream>>>(qh, kh, Vt, concat);
  }

  // 3) output projection -> d_out (fp32)
  gemm_out_kernel<<<256, 256, 0, stream>>>(concat, Wt + 3 * MB, bO,
                                           (float*)d_out);
}